// Round 27
// baseline (173.937 us; speedup 1.0000x reference)
//
#include <hip/hip_runtime.h>

#define N_ROWS 100000
#define IN_F   8192
#define OUT_F  128
#define NNZ    2000000

#define NBUCK  ((N_ROWS + 127) / 128)                // 782 buckets of 128 rows
#define SEGC   512                                   // slots per (bucket, xcd) segment
#define NCUR   (8 * NBUCK)                           // 6256 cursors
#define TRB    ((IN_F / 32) * (OUT_F / 32))          // 1024 transpose blocks
#define ZBLK   ((NCUR + 255) / 256)                  // 25 cursor-zero blocks
#define RGRID  (((NBUCK + 7) / 8) * 16)              // 1568 reduce blocks
#define RSLOT  64                                    // stripe slots per row (max nnz ~42)

typedef float f32x4 __attribute__((ext_vector_type(4)));
typedef float f32x2 __attribute__((ext_vector_type(2)));

__device__ __forceinline__ unsigned short f32_to_bf16_rne(float f) {
    unsigned u = __float_as_uint(f);
    u += 0x7fffu + ((u >> 16) & 1u);
    return (unsigned short)(u >> 16);
}
__device__ __forceinline__ float bflo(unsigned u) { return __uint_as_float(u << 16); }
__device__ __forceinline__ float bfhi(unsigned u) { return __uint_as_float(u & 0xffff0000u); }

// ---------------------------------------------------------------------------
// pre: blocks [0,TRB) weight transpose f32 -> bf16; blocks [TRB,TRB+ZBLK)
// zero the segment cursors.
// ---------------------------------------------------------------------------
__global__ void __launch_bounds__(256) pre_kernel(const float* __restrict__ w,
                                                  unsigned short* __restrict__ wTb,
                                                  int* __restrict__ cur) {
    __shared__ float tile[32 * 33];
    int bid = blockIdx.x, t = threadIdx.x;
    if (bid < TRB) {
        int gx = bid & (IN_F / 32 - 1);              // 256 x-blocks
        int gy = bid >> 8;                           // 4 y-blocks
        int tx = t & 31, ty = t >> 5;                // 32x8
        int x = gx * 32 + tx;
        int y = gy * 32 + ty;
        #pragma unroll
        for (int i = 0; i < 32; i += 8)
            tile[(ty + i) * 33 + tx] = w[(size_t)(y + i) * IN_F + x];
        __syncthreads();
        int ox = gy * 32 + tx;
        int oy = gx * 32 + ty;
        #pragma unroll
        for (int i = 0; i < 32; i += 8)
            wTb[(size_t)(oy + i) * OUT_F + ox] = f32_to_bf16_rne(tile[tx * 33 + ty + i]);
    } else {
        int i = (bid - TRB) * 256 + t;
        if (i < NCUR) cur[i] = 0;
    }
}

// ---------------------------------------------------------------------------
// scatter records into fixed-capacity (bucket, xcd) segments. Segment (b,j)
// and cursor row cur[j][*] are written ONLY by XCD j (= blockIdx&7):
// cursor lines + segment lines stay in one L2, fill fully, write back once
// (r5's proven mechanism — no cross-XCD partial-line amplification).
// record = ((r&127)<<13 | c, val)
// ---------------------------------------------------------------------------
__global__ void __launch_bounds__(256) scatter_seg(const int* __restrict__ rows,
                                                   const int* __restrict__ cols,
                                                   const float* __restrict__ vals,
                                                   int* __restrict__ cur,
                                                   int2* __restrict__ seg) {
    int i = blockIdx.x * 256 + threadIdx.x;
    if (i >= NNZ) return;
    int j = blockIdx.x & 7;                          // == XCD under round-robin
    int r = rows[i];
    int b = r >> 7;
    int p = atomicAdd(&cur[j * NBUCK + b], 1);
    if (p < SEGC)                                    // mean 320, +10.7 sigma; never hit
        seg[((size_t)b * 8 + j) * SEGC + p] =
            make_int2(((r & 127) << 13) | cols[i], __float_as_int(vals[i]));
}

// ---------------------------------------------------------------------------
// FUSED fill+reduce (HALF-BUCKET, 512 thr, XCD-PAIRED): bid -> bucket
// b=(bid&7)+8*(bid>>4), half=(bid>>3)&1 (both halves of a bucket on one XCD;
// second half's segment reads L2-hit). Fill: iterate the bucket's 8
// segments, filter my half, rank=atomicAdd(c2[row]), stripe write
// stB[row*64+rank]=(c<<8,val). Reduce: 8 waves x 8 rows, quarter-wave
// records, uniform ds_read broadcast + uint4 bf16 gather + packed f32x2 FMA.
// ---------------------------------------------------------------------------
__global__ void __launch_bounds__(512) bucket_reduce(const int2* __restrict__ seg,
                                                     const int* __restrict__ cur,
                                                     const unsigned short* __restrict__ wTb,
                                                     const float* __restrict__ bias,
                                                     float* __restrict__ out) {
    __shared__ int2 stB[64 * RSLOT];                 // 32 KB, row-striped
    __shared__ int c2[64];
    int bid = blockIdx.x, t = threadIdx.x;
    int b = (bid & 7) + ((bid >> 4) << 3);           // bucket; XCD bid%8 == b%8
    if (b >= NBUCK) return;
    int hbit = ((bid >> 3) & 1) << 6;                // 0 or 64: my half's row bit
    if (t < 64) c2[t] = 0;
    __syncthreads();
    // fill: scan the bucket's 8 XCD-segments
    for (int j = 0; j < 8; ++j) {
        int len = cur[j * NBUCK + b];
        if (len > SEGC) len = SEGC;
        const int2* sp = seg + ((size_t)b * 8 + j) * SEGC;
        for (int i = t; i < len; i += 512) {
            int2 rec = sp[i];
            int rl = rec.x >> 13;
            if ((rl & 64) == hbit) {
                int r6 = rl & 63;
                int rank = atomicAdd(&c2[r6], 1);
                if (rank < RSLOT)                    // max row nnz ~42; never hit
                    stB[(r6 << 6) + rank] = make_int2((rec.x & 8191) << 8, rec.y);
            }
        }
    }
    __syncthreads();

    // ---- reduce phase: 8 waves x 8 rows each ----
    int wv = t >> 6, lane = t & 63;
    int quarter = lane >> 4;                         // record k+quarter
    int hl      = lane & 15;                         // cols 8hl..8hl+7
    const char* wbase = (const char*)wTb + (hl << 4);
    const unsigned long long* stB64 = (const unsigned long long*)stB;

    for (int rr = 0; rr < 8; ++rr) {
        int row = (wv << 3) + rr;                    // 0..63 within half
        int wid = (b << 7) + hbit + row;
        if (wid >= N_ROWS) break;                    // wave-uniform
        int st = row << 6;                           // stripe base
        int cnt = c2[row]; if (cnt > RSLOT) cnt = RSLOT;
        int en = st + cnt;
        f32x2 a0 = {0.f, 0.f}, a1 = {0.f, 0.f};
        f32x2 a2 = {0.f, 0.f}, a3 = {0.f, 0.f};
        for (int k = st; k < en; k += 8) {
            #pragma unroll
            for (int g = 0; g < 2; ++g) {
                int idx = k + 4 * g + quarter;
                unsigned long long r = stB64[idx < en ? idx : st];  // broadcast
                unsigned xoff = (unsigned)r;
                float    v = (idx < en) ? __uint_as_float((unsigned)(r >> 32)) : 0.f;
                uint4 w = *(const uint4*)(wbase + xoff);
                f32x2 vv = {v, v};
                a0 += vv * (f32x2){bflo(w.x), bfhi(w.x)};   // v_pk_fma_f32
                a1 += vv * (f32x2){bflo(w.y), bfhi(w.y)};
                a2 += vv * (f32x2){bflo(w.z), bfhi(w.z)};
                a3 += vv * (f32x2){bflo(w.w), bfhi(w.w)};
            }
        }
        #pragma unroll
        for (int d = 16; d <= 32; d <<= 1) {
            a0.x += __shfl_down(a0.x, d, 64); a0.y += __shfl_down(a0.y, d, 64);
            a1.x += __shfl_down(a1.x, d, 64); a1.y += __shfl_down(a1.y, d, 64);
            a2.x += __shfl_down(a2.x, d, 64); a2.y += __shfl_down(a2.y, d, 64);
            a3.x += __shfl_down(a3.x, d, 64); a3.y += __shfl_down(a3.y, d, 64);
        }
        if (quarter == 0) {                          // lanes 0..15
            const f32x4 b0 = *(const f32x4*)(bias + 8 * hl);
            const f32x4 b1 = *(const f32x4*)(bias + 8 * hl + 4);
            f32x4 aL = {a0.x + b0.x, a0.y + b0.y, a1.x + b0.z, a1.y + b0.w};
            f32x4 aH = {a2.x + b1.x, a2.y + b1.y, a3.x + b1.z, a3.y + b1.w};
            f32x4* o = (f32x4*)(out + (size_t)wid * OUT_F) + 2 * hl;
            __builtin_nontemporal_store(aL, o);
            __builtin_nontemporal_store(aH, o + 1);
        }
    }
}

// ---------------------------------------------------------------------------
// fallback (ws too small): bias init + atomic scatter — correct but slow
// ---------------------------------------------------------------------------
__global__ void init_out(float4* __restrict__ out4, const float4* __restrict__ bias4) {
    int i = blockIdx.x * blockDim.x + threadIdx.x;
    if (i >= N_ROWS * OUT_F / 4) return;
    out4[i] = bias4[i & 31];
}

__global__ void scatter_noT(const int* __restrict__ rows, const int* __restrict__ cols,
                            const float* __restrict__ vals, const float* __restrict__ w,
                            float* __restrict__ out) {
    int t    = blockIdx.x * blockDim.x + threadIdx.x;
    int nz   = t >> 5;
    int lane = t & 31;
    if (nz >= NNZ) return;
    int   r = rows[nz];
    int   c = cols[nz];
    float v = vals[nz];
    float* o = out + (size_t)r * OUT_F + lane * 4;
    #pragma unroll
    for (int k = 0; k < 4; ++k) {
        float wv = w[(size_t)(lane * 4 + k) * IN_F + c];
        atomicAdd(o + k, v * wv);
    }
}

extern "C" void kernel_launch(void* const* d_in, const int* in_sizes, int n_in,
                              void* d_out, int out_size, void* d_ws, size_t ws_size,
                              hipStream_t stream) {
    const int*   rows   = (const int*)d_in[0];
    const int*   cols   = (const int*)d_in[1];
    const float* vals   = (const float*)d_in[2];
    const float* weight = (const float*)d_in[3];
    const float* bias   = (const float*)d_in[4];
    float* out = (float*)d_out;

    // workspace layout (~27.7 MB)
    char* ws = (char*)d_ws;
    size_t off = 0;
    unsigned short* wTb = (unsigned short*)(ws + off);
    off += (size_t)IN_F * OUT_F * sizeof(unsigned short);                 // 2 MB
    int* cur = (int*)(ws + off); off += ((size_t)NCUR * 4 + 15) & ~(size_t)15; // 25 KB
    int2* seg = (int2*)(ws + off); off += (size_t)NBUCK * 8 * SEGC * 8;   // 25.6 MB

    if (ws_size >= off) {
        pre_kernel<<<TRB + ZBLK, 256, 0, stream>>>(weight, wTb, cur);
        scatter_seg<<<(NNZ + 255) / 256, 256, 0, stream>>>(rows, cols, vals, cur, seg);
        bucket_reduce<<<RGRID, 512, 0, stream>>>(seg, cur, wTb, bias, out);
    } else {
        int n4 = N_ROWS * OUT_F / 4;
        init_out<<<(n4 + 255) / 256, 256, 0, stream>>>((float4*)out, (const float4*)bias);
        long long total = (long long)NNZ * 32;
        scatter_noT<<<(int)((total + 255) / 256), 256, 0, stream>>>(rows, cols, vals, weight, out);
    }
}

// Round 28
// 82.738 us; speedup vs baseline: 2.1023x; 2.1023x over previous
//
#include <hip/hip_runtime.h>

#define N_ROWS 100000
#define IN_F   8192
#define OUT_F  128
#define NNZ    2000000

#define TILE    4096
#define NTILES  ((NNZ + TILE - 1) / TILE)            // 489
#define NBUCK   ((N_ROWS + 127) / 128)               // 782 buckets of 128 rows
#define FLAT3   (NBUCK * NTILES)                     // 382398
#define SCAN_B  1024
#define NBLK3   ((FLAT3 + SCAN_B - 1) / SCAN_B)      // 374
#define NPAD3   (NBLK3 * SCAN_B)                     // 382976
#define TRB     ((IN_F / 32) * (OUT_F / 32))         // 1024 transpose blocks
#define RGRID   (((NBUCK + 7) / 8) * 16)             // 1568 reduce blocks
#define RSLOT   64                                   // slots per row (max nnz ~42)

typedef float f32x4 __attribute__((ext_vector_type(4)));
typedef float f32x2 __attribute__((ext_vector_type(2)));

__device__ __forceinline__ unsigned short f32_to_bf16_rne(float f) {
    unsigned u = __float_as_uint(f);
    u += 0x7fffu + ((u >> 16) & 1u);
    return (unsigned short)(u >> 16);
}
__device__ __forceinline__ float bflo(unsigned u) { return __uint_as_float(u << 16); }
__device__ __forceinline__ float bfhi(unsigned u) { return __uint_as_float(u & 0xffff0000u); }

// XCD-segmented slot for (tile) within a bucket's NTILES-range:
// group j = tile%8 (== writing XCD), slot = P(j) + tile/8,
// P(j) = j*61 + (j?1:0)   [489 tiles: j=0 has 62, j>=1 have 61]
__device__ __forceinline__ int tile_slot(int tile) {
    int j = tile & 7;
    return j * 61 + (j ? 1 : 0) + (tile >> 3);
}

// ---------------------------------------------------------------------------
// fused: blocks [0,NTILES) = per-tile bucket histogram;
//        blocks [NTILES, NTILES+TRB) = weight transpose f32 -> bf16
// ---------------------------------------------------------------------------
__global__ void __launch_bounds__(256) fused_pre(const int* __restrict__ rows,
                                                 int* __restrict__ tileCnt,
                                                 const float* __restrict__ w,
                                                 unsigned short* __restrict__ wTb) {
    __shared__ int smem[32 * 33];
    int bid = blockIdx.x, t = threadIdx.x;
    if (bid < NTILES) {
        int* cnt = smem;
        for (int i = t; i < NBUCK; i += 256) cnt[i] = 0;
        __syncthreads();
        int base = bid * TILE;
        int n = NNZ - base; if (n > TILE) n = TILE;
        for (int i = t; i < n; i += 256) atomicAdd(&cnt[rows[base + i] >> 7], 1);
        __syncthreads();
        int ts = tile_slot(bid);
        for (int i = t; i < NBUCK; i += 256) tileCnt[(size_t)i * NTILES + ts] = cnt[i];
    } else {
        float* tile = (float*)smem;                  // [32][33]
        int b1 = bid - NTILES;
        int gx = b1 & (IN_F / 32 - 1);               // 256 x-blocks
        int gy = b1 >> 8;                            // 4 y-blocks
        int tx = t & 31, ty = t >> 5;                // 32x8
        int x = gx * 32 + tx;
        int y = gy * 32 + ty;
        #pragma unroll
        for (int i = 0; i < 32; i += 8)
            tile[(ty + i) * 33 + tx] = w[(size_t)(y + i) * IN_F + x];
        __syncthreads();
        int ox = gy * 32 + tx;
        int oy = gx * 32 + ty;
        #pragma unroll
        for (int i = 0; i < 32; i += 8)
            wTb[(size_t)(oy + i) * OUT_F + ox] = f32_to_bf16_rne(tile[tx * 33 + ty + i]);
    }
}

// ---------------------------------------------------------------------------
// two-level exclusive scan over tileCnt; out-of-range reads guarded
// ---------------------------------------------------------------------------
__global__ void scan_blocks(int* __restrict__ counts, int* __restrict__ blockSums) {
    __shared__ int sh[SCAN_B];
    int tid = threadIdx.x;
    int gid = blockIdx.x * SCAN_B + tid;
    int v = (gid < FLAT3) ? counts[gid] : 0;
    sh[tid] = v;
    __syncthreads();
    for (int off = 1; off < SCAN_B; off <<= 1) {
        int t = (tid >= off) ? sh[tid - off] : 0;
        __syncthreads();
        sh[tid] += t;
        __syncthreads();
    }
    counts[gid] = sh[tid] - v;
    if (tid == SCAN_B - 1) blockSums[blockIdx.x] = sh[tid];
}

__global__ void scan_sums(int* __restrict__ blockSums) {
    __shared__ int sh[SCAN_B];
    int tid = threadIdx.x;
    int v = (tid < NBLK3) ? blockSums[tid] : 0;
    sh[tid] = v;
    __syncthreads();
    for (int off = 1; off < SCAN_B; off <<= 1) {
        int t = (tid >= off) ? sh[tid - off] : 0;
        __syncthreads();
        sh[tid] += t;
        __syncthreads();
    }
    blockSums[tid] = sh[tid] - v;
}

// ---------------------------------------------------------------------------
// B: partition tile into bucket-blocked layout. Each (bucket, xcd) segment
// is written ONLY by tiles on that XCD (tile%8), consecutive-tile runs
// adjacent -> full-line writebacks (r5 mechanism). record=((r&127)<<13|c,val)
// ---------------------------------------------------------------------------
__global__ void __launch_bounds__(256) partition_tiles(const int* __restrict__ rows,
                                                       const int* __restrict__ cols,
                                                       const float* __restrict__ vals,
                                                       const int* __restrict__ scanned,
                                                       const int* __restrict__ bsum,
                                                       int2* __restrict__ pairs) {
    __shared__ int2 stage[TILE];                     // 32 KB
    __shared__ unsigned short sb[TILE];              // 8 KB
    __shared__ int lcnt[NBUCK];
    __shared__ int loff[1024];
    __shared__ int c2[NBUCK];
    __shared__ int gst[NBUCK];
    int tile = blockIdx.x, t = threadIdx.x;
    int ts = tile_slot(tile);
    for (int i = t; i < NBUCK; i += 256) {
        lcnt[i] = 0; c2[i] = 0;
        int idx = i * NTILES + ts;
        gst[i] = scanned[idx] + bsum[idx >> 10];
    }
    __syncthreads();
    int base = tile * TILE;
    int n = NNZ - base; if (n > TILE) n = TILE;
    for (int i = t; i < n; i += 256) atomicAdd(&lcnt[rows[base + i] >> 7], 1);
    __syncthreads();
    for (int i = t; i < 1024; i += 256) loff[i] = (i < NBUCK) ? lcnt[i] : 0;
    __syncthreads();
    for (int off = 1; off < 1024; off <<= 1) {
        int v0 = loff[t],       m0 = (t       >= off) ? loff[t       - off] : 0;
        int v1 = loff[t + 256], m1 = (t + 256 >= off) ? loff[t + 256 - off] : 0;
        int v2 = loff[t + 512], m2 = (t + 512 >= off) ? loff[t + 512 - off] : 0;
        int v3 = loff[t + 768], m3 = (t + 768 >= off) ? loff[t + 768 - off] : 0;
        __syncthreads();
        loff[t] = v0 + m0; loff[t + 256] = v1 + m1;
        loff[t + 512] = v2 + m2; loff[t + 768] = v3 + m3;
        __syncthreads();
    }
    for (int i = t; i < NBUCK; i += 256) loff[i] -= lcnt[i];
    __syncthreads();
    for (int i = t; i < n; i += 256) {
        int r = rows[base + i];
        int bk = r >> 7;
        int rank = atomicAdd(&c2[bk], 1);
        int s = loff[bk] + rank;
        stage[s] = make_int2(((r & 127) << 13) | cols[base + i],
                             __float_as_int(vals[base + i]));
        sb[s] = (unsigned short)bk;
    }
    __syncthreads();
    for (int s = t; s < n; s += 256) {
        int bk = sb[s];
        pairs[gst[bk] + (s - loff[bk])] = stage[s];
    }
}

// ---------------------------------------------------------------------------
// C (FUSED single-pass sort+reduce, HALF-BUCKET, 512 thr, XCD-PAIRED):
// bid -> b=(bid&7)+8*(bid>>4), half=(bid>>3)&1; both halves of a bucket on
// the same XCD (r24's proven mapping). NO histogram pass, NO scan: each row
// owns a fixed 64-slot stripe of stB; placement is one atomicAdd + write.
//   pass: read span once, filter my half, rank=atomicAdd(c2[row]),
//         stB[row*64+rank] = (c<<8, val)
//   reduce: 8 waves x 8 rows from the stripes, quarter-wave records,
//         uniform ds_read broadcast + uint4 bf16 gather + packed f32x2 FMA
// ---------------------------------------------------------------------------
__global__ void __launch_bounds__(512) bucket_reduce(const int2* __restrict__ pairs,
                                                     const int* __restrict__ scanned,
                                                     const int* __restrict__ bsum,
                                                     const unsigned short* __restrict__ wTb,
                                                     const float* __restrict__ bias,
                                                     float* __restrict__ out) {
    __shared__ int2 stB[64 * RSLOT];                 // 32 KB, row-striped
    __shared__ int c2[64];
    int bid = blockIdx.x, t = threadIdx.x;
    int b = (bid & 7) + ((bid >> 4) << 3);           // bucket; XCD bid%8 == b%8
    if (b >= NBUCK) return;
    int hbit = ((bid >> 3) & 1) << 6;                // 0 or 64: my half's row bit
    int i0 = b * NTILES;
    int base = scanned[i0] + bsum[i0 >> 10];
    int end;
    if (b + 1 < NBUCK) { int i1 = (b + 1) * NTILES; end = scanned[i1] + bsum[i1 >> 10]; }
    else end = NNZ;
    int n = end - base;
    if (t < 64) c2[t] = 0;
    __syncthreads();
    // single pass: scatter my half's records into fixed row stripes
    for (int i = t; i < n; i += 512) {
        int2 rec = pairs[base + i];
        int rl = rec.x >> 13;
        if ((rl & 64) == hbit) {
            int r6 = rl & 63;
            int rank = atomicAdd(&c2[r6], 1);
            if (rank < RSLOT)                        // max row nnz ~42; never hit
                stB[(r6 << 6) + rank] = make_int2((rec.x & 8191) << 8, rec.y);
        }
    }
    __syncthreads();

    // ---- reduce phase: 8 waves x 8 rows each ----
    int wv = t >> 6, lane = t & 63;
    int quarter = lane >> 4;                         // record k+quarter
    int hl      = lane & 15;                         // cols 8hl..8hl+7
    const char* wbase = (const char*)wTb + (hl << 4);
    const unsigned long long* stB64 = (const unsigned long long*)stB;

    for (int rr = 0; rr < 8; ++rr) {
        int row = (wv << 3) + rr;                    // 0..63 within half
        int wid = (b << 7) + hbit + row;
        if (wid >= N_ROWS) break;                    // wave-uniform
        int st = row << 6;                           // stripe base
        int cnt = c2[row]; if (cnt > RSLOT) cnt = RSLOT;
        int en = st + cnt;
        f32x2 a0 = {0.f, 0.f}, a1 = {0.f, 0.f};
        f32x2 a2 = {0.f, 0.f}, a3 = {0.f, 0.f};
        for (int k = st; k < en; k += 8) {
            #pragma unroll
            for (int g = 0; g < 2; ++g) {
                int idx = k + 4 * g + quarter;
                unsigned long long r = stB64[idx < en ? idx : st];  // broadcast
                unsigned xoff = (unsigned)r;
                float    v = (idx < en) ? __uint_as_float((unsigned)(r >> 32)) : 0.f;
                uint4 w = *(const uint4*)(wbase + xoff);
                f32x2 vv = {v, v};
                a0 += vv * (f32x2){bflo(w.x), bfhi(w.x)};   // v_pk_fma_f32
                a1 += vv * (f32x2){bflo(w.y), bfhi(w.y)};
                a2 += vv * (f32x2){bflo(w.z), bfhi(w.z)};
                a3 += vv * (f32x2){bflo(w.w), bfhi(w.w)};
            }
        }
        #pragma unroll
        for (int d = 16; d <= 32; d <<= 1) {
            a0.x += __shfl_down(a0.x, d, 64); a0.y += __shfl_down(a0.y, d, 64);
            a1.x += __shfl_down(a1.x, d, 64); a1.y += __shfl_down(a1.y, d, 64);
            a2.x += __shfl_down(a2.x, d, 64); a2.y += __shfl_down(a2.y, d, 64);
            a3.x += __shfl_down(a3.x, d, 64); a3.y += __shfl_down(a3.y, d, 64);
        }
        if (quarter == 0) {                          // lanes 0..15
            const f32x4 b0 = *(const f32x4*)(bias + 8 * hl);
            const f32x4 b1 = *(const f32x4*)(bias + 8 * hl + 4);
            f32x4 aL = {a0.x + b0.x, a0.y + b0.y, a1.x + b0.z, a1.y + b0.w};
            f32x4 aH = {a2.x + b1.x, a2.y + b1.y, a3.x + b1.z, a3.y + b1.w};
            f32x4* o = (f32x4*)(out + (size_t)wid * OUT_F) + 2 * hl;
            __builtin_nontemporal_store(aL, o);
            __builtin_nontemporal_store(aH, o + 1);
        }
    }
}

// ---------------------------------------------------------------------------
// fallback (ws too small): bias init + atomic scatter — correct but slow
// ---------------------------------------------------------------------------
__global__ void init_out(float4* __restrict__ out4, const float4* __restrict__ bias4) {
    int i = blockIdx.x * blockDim.x + threadIdx.x;
    if (i >= N_ROWS * OUT_F / 4) return;
    out4[i] = bias4[i & 31];
}

__global__ void scatter_noT(const int* __restrict__ rows, const int* __restrict__ cols,
                            const float* __restrict__ vals, const float* __restrict__ w,
                            float* __restrict__ out) {
    int t    = blockIdx.x * blockDim.x + threadIdx.x;
    int nz   = t >> 5;
    int lane = t & 31;
    if (nz >= NNZ) return;
    int   r = rows[nz];
    int   c = cols[nz];
    float v = vals[nz];
    float* o = out + (size_t)r * OUT_F + lane * 4;
    #pragma unroll
    for (int k = 0; k < 4; ++k) {
        float wv = w[(size_t)(lane * 4 + k) * IN_F + c];
        atomicAdd(o + k, v * wv);
    }
}

extern "C" void kernel_launch(void* const* d_in, const int* in_sizes, int n_in,
                              void* d_out, int out_size, void* d_ws, size_t ws_size,
                              hipStream_t stream) {
    const int*   rows   = (const int*)d_in[0];
    const int*   cols   = (const int*)d_in[1];
    const float* vals   = (const float*)d_in[2];
    const float* weight = (const float*)d_in[3];
    const float* bias   = (const float*)d_in[4];
    float* out = (float*)d_out;

    // workspace layout (~20 MB)
    char* ws = (char*)d_ws;
    size_t off = 0;
    unsigned short* wTb = (unsigned short*)(ws + off);
    off += (size_t)IN_F * OUT_F * sizeof(unsigned short);                 // 2 MB
    int* tileCnt   = (int*)(ws + off); off += (size_t)NPAD3 * 4;          // 1.53 MB
    int* blockSums = (int*)(ws + off); off += (size_t)SCAN_B * 4;         // 4 KB
    off = (off + 15) & ~(size_t)15;
    int2* pairs    = (int2*)(ws + off); off += (size_t)NNZ * 8;           // 16 MB

    if (ws_size >= off) {
        fused_pre<<<NTILES + TRB, 256, 0, stream>>>(rows, tileCnt, weight, wTb);
        scan_blocks<<<NBLK3, SCAN_B, 0, stream>>>(tileCnt, blockSums);
        scan_sums<<<1, SCAN_B, 0, stream>>>(blockSums);
        partition_tiles<<<NTILES, 256, 0, stream>>>(rows, cols, vals, tileCnt,
                                                    blockSums, pairs);
        bucket_reduce<<<RGRID, 512, 0, stream>>>(pairs, tileCnt, blockSums,
                                                 wTb, bias, out);
    } else {
        int n4 = N_ROWS * OUT_F / 4;
        init_out<<<(n4 + 255) / 256, 256, 0, stream>>>((float4*)out, (const float4*)bias);
        long long total = (long long)NNZ * 32;
        scatter_noT<<<(int)((total + 255) / 256), 256, 0, stream>>>(rows, cols, vals, weight, out);
    }
}

// Round 29
// 77.862 us; speedup vs baseline: 2.2339x; 1.0626x over previous
//
#include <hip/hip_runtime.h>

#define N_ROWS 100000
#define IN_F   8192
#define OUT_F  128
#define NNZ    2000000

#define TILE   4096
#define NTILES ((NNZ + TILE - 1) / TILE)             // 489
#define NBUCK  ((N_ROWS + 127) / 128)                // 782 buckets of 128 rows
#define SEGC   512                                   // (bucket,xcd) seg capacity (mean 320, +10.7s)
#define NCUR   (8 * NBUCK)                           // 6256 cursors
#define TRB    ((IN_F / 32) * (OUT_F / 32))          // 1024 transpose blocks
#define ZBLK   ((NCUR + 255) / 256)                  // 25 cursor-zero blocks
#define RGRID  (((NBUCK + 7) / 8) * 16)              // 1568 reduce blocks
#define RSLOT  64                                    // stripe slots per row (max nnz ~42)

typedef float f32x4 __attribute__((ext_vector_type(4)));
typedef float f32x2 __attribute__((ext_vector_type(2)));

__device__ __forceinline__ unsigned short f32_to_bf16_rne(float f) {
    unsigned u = __float_as_uint(f);
    u += 0x7fffu + ((u >> 16) & 1u);
    return (unsigned short)(u >> 16);
}
__device__ __forceinline__ float bflo(unsigned u) { return __uint_as_float(u << 16); }
__device__ __forceinline__ float bfhi(unsigned u) { return __uint_as_float(u & 0xffff0000u); }

// ---------------------------------------------------------------------------
// pre: blocks [0,TRB) weight transpose f32 -> bf16; blocks [TRB,TRB+ZBLK)
// zero the segment cursors.
// ---------------------------------------------------------------------------
__global__ void __launch_bounds__(256) pre_kernel(const float* __restrict__ w,
                                                  unsigned short* __restrict__ wTb,
                                                  int* __restrict__ cur) {
    __shared__ float tile[32 * 33];
    int bid = blockIdx.x, t = threadIdx.x;
    if (bid < TRB) {
        int gx = bid & (IN_F / 32 - 1);              // 256 x-blocks
        int gy = bid >> 8;                           // 4 y-blocks
        int tx = t & 31, ty = t >> 5;                // 32x8
        int x = gx * 32 + tx;
        int y = gy * 32 + ty;
        #pragma unroll
        for (int i = 0; i < 32; i += 8)
            tile[(ty + i) * 33 + tx] = w[(size_t)(y + i) * IN_F + x];
        __syncthreads();
        int ox = gy * 32 + tx;
        int oy = gx * 32 + ty;
        #pragma unroll
        for (int i = 0; i < 32; i += 8)
            wTb[(size_t)(oy + i) * OUT_F + ox] = f32_to_bf16_rne(tile[tx * 33 + ty + i]);
    } else {
        int i = (bid - TRB) * 256 + t;
        if (i < NCUR) cur[i] = 0;
    }
}

// ---------------------------------------------------------------------------
// partition with CHUNK RESERVATION (replaces tile_hist + 2 scans + exact
// placement): stage tile's records bucket-sorted in LDS (proven r20 code),
// then ONE atomicAdd(cur[xcd][bucket], lcnt[bucket]) per bucket reserves a
// contiguous run in segment (bucket, xcd=tile%8); write runs coalesced.
// 382k atomics total (chains ~61 deep, vs r27's 2M at 320 deep); same-XCD
// tiles append adjacently -> lines fill in one L2 (r5 mechanism).
// record = ((r&127)<<13 | c, val); order within bucket is irrelevant.
// ---------------------------------------------------------------------------
__global__ void __launch_bounds__(256) partition_reserve(const int* __restrict__ rows,
                                                         const int* __restrict__ cols,
                                                         const float* __restrict__ vals,
                                                         int* __restrict__ cur,
                                                         int2* __restrict__ seg) {
    __shared__ int2 stage[TILE];                     // 32 KB
    __shared__ unsigned short sb[TILE];              // 8 KB
    __shared__ int lcnt[NBUCK];
    __shared__ int loff[1024];
    __shared__ int c2[NBUCK];
    __shared__ int gst[NBUCK];
    int tile = blockIdx.x, t = threadIdx.x;
    int jx = tile & 7;                               // XCD under round-robin
    for (int i = t; i < NBUCK; i += 256) { lcnt[i] = 0; c2[i] = 0; }
    __syncthreads();
    int base = tile * TILE;
    int n = NNZ - base; if (n > TILE) n = TILE;
    for (int i = t; i < n; i += 256) atomicAdd(&lcnt[rows[base + i] >> 7], 1);
    __syncthreads();
    // reserve my runs (one atomic per bucket) — replaces the global scan
    for (int i = t; i < NBUCK; i += 256)
        gst[i] = atomicAdd(&cur[jx * NBUCK + i], lcnt[i]);
    // local exclusive scan for staging layout
    for (int i = t; i < 1024; i += 256) loff[i] = (i < NBUCK) ? lcnt[i] : 0;
    __syncthreads();
    for (int off = 1; off < 1024; off <<= 1) {
        int v0 = loff[t],       m0 = (t       >= off) ? loff[t       - off] : 0;
        int v1 = loff[t + 256], m1 = (t + 256 >= off) ? loff[t + 256 - off] : 0;
        int v2 = loff[t + 512], m2 = (t + 512 >= off) ? loff[t + 512 - off] : 0;
        int v3 = loff[t + 768], m3 = (t + 768 >= off) ? loff[t + 768 - off] : 0;
        __syncthreads();
        loff[t] = v0 + m0; loff[t + 256] = v1 + m1;
        loff[t + 512] = v2 + m2; loff[t + 768] = v3 + m3;
        __syncthreads();
    }
    for (int i = t; i < NBUCK; i += 256) loff[i] -= lcnt[i];
    __syncthreads();
    for (int i = t; i < n; i += 256) {
        int r = rows[base + i];
        int bk = r >> 7;
        int rank = atomicAdd(&c2[bk], 1);
        int s = loff[bk] + rank;
        stage[s] = make_int2(((r & 127) << 13) | cols[base + i],
                             __float_as_int(vals[base + i]));
        sb[s] = (unsigned short)bk;
    }
    __syncthreads();
    // coalesced run-writes into per-(bucket,xcd) segments
    for (int s = t; s < n; s += 256) {
        int bk = sb[s];
        int pos = gst[bk] + (s - loff[bk]);
        if (pos < SEGC)                              // +10.7 sigma; never hit
            seg[((size_t)bk * 8 + jx) * SEGC + pos] = stage[s];
    }
}

// ---------------------------------------------------------------------------
// FUSED fill+reduce (HALF-BUCKET, 512 thr, XCD-PAIRED): bid -> bucket
// b=(bid&7)+8*(bid>>4), half=(bid>>3)&1 (both halves on one XCD; second
// half's segment reads L2-hit). Fill: iterate the bucket's 8 segments,
// filter my half, rank=atomicAdd(c2[row]), stripe write stB[row*64+rank].
// Reduce: 8 waves x 8 rows, quarter-wave records, uniform ds_read broadcast
// + uint4 bf16 gather + packed f32x2 FMA (r26's proven loop).
// ---------------------------------------------------------------------------
__global__ void __launch_bounds__(512) bucket_reduce(const int2* __restrict__ seg,
                                                     const int* __restrict__ cur,
                                                     const unsigned short* __restrict__ wTb,
                                                     const float* __restrict__ bias,
                                                     float* __restrict__ out) {
    __shared__ int2 stB[64 * RSLOT];                 // 32 KB, row-striped
    __shared__ int c2[64];
    int bid = blockIdx.x, t = threadIdx.x;
    int b = (bid & 7) + ((bid >> 4) << 3);           // bucket; XCD bid%8 == b%8
    if (b >= NBUCK) return;
    int hbit = ((bid >> 3) & 1) << 6;                // 0 or 64: my half's row bit
    if (t < 64) c2[t] = 0;
    __syncthreads();
    // fill: scan the bucket's 8 XCD-segments
    for (int j = 0; j < 8; ++j) {
        int len = cur[j * NBUCK + b];
        if (len > SEGC) len = SEGC;
        const int2* sp = seg + ((size_t)b * 8 + j) * SEGC;
        for (int i = t; i < len; i += 512) {
            int2 rec = sp[i];
            int rl = rec.x >> 13;
            if ((rl & 64) == hbit) {
                int r6 = rl & 63;
                int rank = atomicAdd(&c2[r6], 1);
                if (rank < RSLOT)                    // max row nnz ~42; never hit
                    stB[(r6 << 6) + rank] = make_int2((rec.x & 8191) << 8, rec.y);
            }
        }
    }
    __syncthreads();

    // ---- reduce phase: 8 waves x 8 rows each ----
    int wv = t >> 6, lane = t & 63;
    int quarter = lane >> 4;                         // record k+quarter
    int hl      = lane & 15;                         // cols 8hl..8hl+7
    const char* wbase = (const char*)wTb + (hl << 4);
    const unsigned long long* stB64 = (const unsigned long long*)stB;

    for (int rr = 0; rr < 8; ++rr) {
        int row = (wv << 3) + rr;                    // 0..63 within half
        int wid = (b << 7) + hbit + row;
        if (wid >= N_ROWS) break;                    // wave-uniform
        int st = row << 6;                           // stripe base
        int cnt = c2[row]; if (cnt > RSLOT) cnt = RSLOT;
        int en = st + cnt;
        f32x2 a0 = {0.f, 0.f}, a1 = {0.f, 0.f};
        f32x2 a2 = {0.f, 0.f}, a3 = {0.f, 0.f};
        for (int k = st; k < en; k += 8) {
            #pragma unroll
            for (int g = 0; g < 2; ++g) {
                int idx = k + 4 * g + quarter;
                unsigned long long r = stB64[idx < en ? idx : st];  // broadcast
                unsigned xoff = (unsigned)r;
                float    v = (idx < en) ? __uint_as_float((unsigned)(r >> 32)) : 0.f;
                uint4 w = *(const uint4*)(wbase + xoff);
                f32x2 vv = {v, v};
                a0 += vv * (f32x2){bflo(w.x), bfhi(w.x)};   // v_pk_fma_f32
                a1 += vv * (f32x2){bflo(w.y), bfhi(w.y)};
                a2 += vv * (f32x2){bflo(w.z), bfhi(w.z)};
                a3 += vv * (f32x2){bflo(w.w), bfhi(w.w)};
            }
        }
        #pragma unroll
        for (int d = 16; d <= 32; d <<= 1) {
            a0.x += __shfl_down(a0.x, d, 64); a0.y += __shfl_down(a0.y, d, 64);
            a1.x += __shfl_down(a1.x, d, 64); a1.y += __shfl_down(a1.y, d, 64);
            a2.x += __shfl_down(a2.x, d, 64); a2.y += __shfl_down(a2.y, d, 64);
            a3.x += __shfl_down(a3.x, d, 64); a3.y += __shfl_down(a3.y, d, 64);
        }
        if (quarter == 0) {                          // lanes 0..15
            const f32x4 b0 = *(const f32x4*)(bias + 8 * hl);
            const f32x4 b1 = *(const f32x4*)(bias + 8 * hl + 4);
            f32x4 aL = {a0.x + b0.x, a0.y + b0.y, a1.x + b0.z, a1.y + b0.w};
            f32x4 aH = {a2.x + b1.x, a2.y + b1.y, a3.x + b1.z, a3.y + b1.w};
            f32x4* o = (f32x4*)(out + (size_t)wid * OUT_F) + 2 * hl;
            __builtin_nontemporal_store(aL, o);
            __builtin_nontemporal_store(aH, o + 1);
        }
    }
}

// ---------------------------------------------------------------------------
// fallback (ws too small): bias init + atomic scatter — correct but slow
// ---------------------------------------------------------------------------
__global__ void init_out(float4* __restrict__ out4, const float4* __restrict__ bias4) {
    int i = blockIdx.x * blockDim.x + threadIdx.x;
    if (i >= N_ROWS * OUT_F / 4) return;
    out4[i] = bias4[i & 31];
}

__global__ void scatter_noT(const int* __restrict__ rows, const int* __restrict__ cols,
                            const float* __restrict__ vals, const float* __restrict__ w,
                            float* __restrict__ out) {
    int t    = blockIdx.x * blockDim.x + threadIdx.x;
    int nz   = t >> 5;
    int lane = t & 31;
    if (nz >= NNZ) return;
    int   r = rows[nz];
    int   c = cols[nz];
    float v = vals[nz];
    float* o = out + (size_t)r * OUT_F + lane * 4;
    #pragma unroll
    for (int k = 0; k < 4; ++k) {
        float wv = w[(size_t)(lane * 4 + k) * IN_F + c];
        atomicAdd(o + k, v * wv);
    }
}

extern "C" void kernel_launch(void* const* d_in, const int* in_sizes, int n_in,
                              void* d_out, int out_size, void* d_ws, size_t ws_size,
                              hipStream_t stream) {
    const int*   rows   = (const int*)d_in[0];
    const int*   cols   = (const int*)d_in[1];
    const float* vals   = (const float*)d_in[2];
    const float* weight = (const float*)d_in[3];
    const float* bias   = (const float*)d_in[4];
    float* out = (float*)d_out;

    // workspace layout (~27.7 MB)
    char* ws = (char*)d_ws;
    size_t off = 0;
    unsigned short* wTb = (unsigned short*)(ws + off);
    off += (size_t)IN_F * OUT_F * sizeof(unsigned short);                 // 2 MB
    int* cur = (int*)(ws + off); off += ((size_t)NCUR * 4 + 15) & ~(size_t)15; // 25 KB
    int2* seg = (int2*)(ws + off); off += (size_t)NBUCK * 8 * SEGC * 8;   // 25.6 MB

    if (ws_size >= off) {
        pre_kernel<<<TRB + ZBLK, 256, 0, stream>>>(weight, wTb, cur);
        partition_reserve<<<NTILES, 256, 0, stream>>>(rows, cols, vals, cur, seg);
        bucket_reduce<<<RGRID, 512, 0, stream>>>(seg, cur, wTb, bias, out);
    } else {
        int n4 = N_ROWS * OUT_F / 4;
        init_out<<<(n4 + 255) / 256, 256, 0, stream>>>((float4*)out, (const float4*)bias);
        long long total = (long long)NNZ * 32;
        scatter_noT<<<(int)((total + 255) / 256), 256, 0, stream>>>(rows, cols, vals, weight, out);
    }
}